// Round 6
// baseline (346.681 us; speedup 1.0000x reference)
//
#include <hip/hip_runtime.h>
#include <hip/hip_bf16.h>
#include <math.h>

#define B_   32
#define L_   512
#define C_   862
#define P_   720
#define H2_  1024
#define M_   (B_*C_)     // 27584 real rows
#define MP_  27648       // padded to multiple of 256
#define PP_  768         // P padded to multiple of 256

typedef __hip_bfloat16 bf16;
typedef __attribute__((ext_vector_type(8))) short s16x8;
typedef __attribute__((ext_vector_type(4))) float f32x4;

__device__ __forceinline__ void gload_lds16(const bf16* g, bf16* lds) {
    __builtin_amdgcn_global_load_lds(
        (const __attribute__((address_space(1))) void*)g,
        (__attribute__((address_space(3))) void*)lds, 16, 0, 0);
}
__device__ __forceinline__ unsigned short f2b(float f) {
    bf16 h = __float2bfloat16(f);
    return *reinterpret_cast<unsigned short*>(&h);
}
__device__ __forceinline__ float b2f_lo(unsigned int u) {
    return __uint_as_float((u & 0xffffu) << 16);
}
__device__ __forceinline__ float b2f_hi(unsigned int u) {
    return __uint_as_float(u & 0xffff0000u);
}

// ---------------------------------------------------------------- DCT matrix (bf16)
__global__ __launch_bounds__(256) void build_dct(bf16* __restrict__ D) {
    int idx = blockIdx.x * 256 + threadIdx.x;
    if (idx >= L_ * L_) return;
    int k = idx >> 9, l = idx & 511;
    double ang = M_PI * (double)((2 * l + 1) * k) / (2.0 * (double)L_);
    D[idx] = __float2bfloat16((float)(2.0 * cos(ang)));
}

// ------------------------------------------------------------- fp32 -> bf16 convert
__global__ __launch_bounds__(256) void cvt_bf16(const float* __restrict__ in,
                                                bf16* __restrict__ out, int n) {
    int i = blockIdx.x * 256 + threadIdx.x;
    if (i < n) out[i] = __float2bfloat16(in[i]);
}

// Wl (720,512) -> bf16 padded to (768,512) with zeros
__global__ __launch_bounds__(256) void cvt_wl_pad(const float* __restrict__ in,
                                                  bf16* __restrict__ out) {
    int i = blockIdx.x * 256 + threadIdx.x;
    if (i >= PP_ * L_) return;
    int r = i >> 9;
    out[i] = (r < P_) ? __float2bfloat16(in[i]) : __float2bfloat16(0.f);
}

// ---------------------------------------------------- x (B,L,C) -> Xc (B*C,L) bf16
__global__ __launch_bounds__(256) void transpose_x(const float* __restrict__ x,
                                                   bf16* __restrict__ Xc) {
    __shared__ float tile[32][33];
    int b  = blockIdx.z;
    int c0 = blockIdx.x * 32;
    int l0 = blockIdx.y * 32;
    int tx = threadIdx.x & 31, ty = threadIdx.x >> 5;   // 32 x 8
#pragma unroll
    for (int i = 0; i < 4; ++i) {
        int l = l0 + ty + i * 8, c = c0 + tx;
        float v = 0.f;
        if (l < L_ && c < C_) v = x[((size_t)b * L_ + l) * C_ + c];
        tile[ty + i * 8][tx] = v;
    }
    __syncthreads();
#pragma unroll
    for (int i = 0; i < 4; ++i) {
        int c = c0 + ty + i * 8, l = l0 + tx;
        if (c < C_ && l < L_)
            Xc[((size_t)b * C_ + c) * L_ + l] = __float2bfloat16(tile[tx][ty + i * 8]);
    }
}

// ------------------- row LayerNorm (512), bf16 in -> bf16 out; MUL: multiply by Xc
template <bool MUL>
__global__ __launch_bounds__(256) void layernorm_bf(const bf16* __restrict__ X,
                                                    const bf16* __restrict__ Xc,
                                                    const float* __restrict__ gamma,
                                                    const float* __restrict__ beta,
                                                    bf16* __restrict__ Out) {
    int row = blockIdx.x, tid = threadIdx.x;
    unsigned int u = ((const unsigned int*)(X + (size_t)row * L_))[tid];
    float v0 = b2f_lo(u), v1 = b2f_hi(u);
    float s = v0 + v1, q = v0 * v0 + v1 * v1;
#pragma unroll
    for (int off = 32; off; off >>= 1) {
        s += __shfl_down(s, off);
        q += __shfl_down(q, off);
    }
    __shared__ float ss[4], sq[4];
    int wid = tid >> 6, lane = tid & 63;
    if (lane == 0) { ss[wid] = s; sq[wid] = q; }
    __syncthreads();
    if (tid == 0) {
        float S = ss[0] + ss[1] + ss[2] + ss[3];
        float Q = sq[0] + sq[1] + sq[2] + sq[3];
        float mu  = S * (1.f / L_);
        float var = Q * (1.f / L_) - mu * mu;
        ss[0] = mu;
        sq[0] = rsqrtf(var + 1e-6f);
    }
    __syncthreads();
    float mu = ss[0], r = sq[0];
    float2 gm = ((const float2*)gamma)[tid];
    float2 bt = ((const float2*)beta)[tid];
    float y0 = (v0 - mu) * r * gm.x + bt.x;
    float y1 = (v1 - mu) * r * gm.y + bt.y;
    if (MUL) {
        unsigned int xu = ((const unsigned int*)(Xc + (size_t)row * L_))[tid];
        y0 *= b2f_lo(xu);
        y1 *= b2f_hi(xu);
    }
    unsigned int o = ((unsigned int)f2b(y1) << 16) | f2b(y0);
    ((unsigned int*)(Out + (size_t)row * L_))[tid] = o;
}

// ------------------------------------------------- swapped GEMM, K=512 per dispatch
// out[n', m'] = act( S[m',koff:koff+512] . G[n',koff:koff+512] )
// S (small, weights) -> registers af[2][16], preloaded once, reused across panels.
// G (large, activations) -> LDS panels 64x512 bf16, double-buffered, staged by
// global_load_lds with inverse-swizzled source (slot ^= row&7); reads swizzled.
// Block: 512 thr / 8 waves; wave owns 32 m' x 64 n'. One barrier per panel.
// OUTMODE: 0 = bf16 linear [n'][MS] (ACT: 0 none, 1 relu)
//          1 = f32 linear (partial)
//          2 = read partial, add, sigmoid, bf16 linear
//          3 = scatter: out[b][m'][c] (n'->(b,c)) + bias[m'] (f32)
template <int ACT, int OUTMODE>
__global__ __launch_bounds__(512, 2)
void gemm_sw(const bf16* __restrict__ S, int s_stride,
             const bf16* __restrict__ Gm, int g_stride, int koff,
             const float* __restrict__ partial, const float* __restrict__ bias,
             void* __restrict__ Out, int MS, int PPB, int Nreal, int Mreal) {
    __shared__ bf16 panel[2][64][512];      // 128 KiB
    int tid = threadIdx.x, wave = tid >> 6, lane = tid & 63;
    int fr = lane & 15, kq = lane >> 4;     // fragment row / k-quad
    int smrow = blockIdx.x * 256 + wave * 32;

    // ---- preload S fragments (af): 32 x 16B global loads, L2-hot
    s16x8 af[2][16];
    {
        const char* Sb = (const char*)S + (size_t)koff * 2 + kq * 16;
        size_t srowb = (size_t)s_stride * 2;
#pragma unroll
        for (int i = 0; i < 2; ++i) {
            const char* base = Sb + (size_t)(smrow + i * 16 + fr) * srowb;
#pragma unroll
            for (int t = 0; t < 16; ++t)
                af[i][t] = *reinterpret_cast<const s16x8*>(base + t * 64);
        }
    }

    size_t growb = (size_t)g_stride * 2;
    const char* Gb = (const char*)Gm + (size_t)koff * 2;
    int p0 = blockIdx.y * PPB;
    int rr = wave * 8;                      // this wave stages rows rr..rr+7

#define STAGEP(bufi, p)                                                          \
    do {                                                                         \
        _Pragma("unroll")                                                        \
        for (int q_ = 0; q_ < 8; ++q_) {                                         \
            int r_ = rr + q_;                                                    \
            gload_lds16((const bf16*)(Gb + (size_t)((p) * 64 + r_) * growb       \
                                      + ((lane ^ (r_ & 7)) << 4)),               \
                        &panel[bufi][r_][0]);                                    \
        }                                                                        \
    } while (0)

    STAGEP(0, p0);
    __syncthreads();

    int buf = 0;
    for (int pp = 0; pp < PPB; ++pp) {
        if (pp + 1 < PPB) STAGEP(buf ^ 1, p0 + pp + 1);

        f32x4 acc[2][4] = {};
        const char* Pb = (const char*)panel + buf * (64 * 512 * 2);
#pragma unroll
        for (int t = 0; t < 16; ++t) {
            s16x8 bv[4];
#pragma unroll
            for (int j = 0; j < 4; ++j) {
                int row = j * 16 + fr;
                int sw = (t * 4 + kq) ^ (fr & 7);
                bv[j] = *reinterpret_cast<const s16x8*>(Pb + row * 1024 + (sw << 4));
            }
#pragma unroll
            for (int i = 0; i < 2; ++i)
#pragma unroll
                for (int j = 0; j < 4; ++j)
                    acc[i][j] = __builtin_amdgcn_mfma_f32_16x16x32_bf16(af[i][t], bv[j], acc[i][j], 0, 0, 0);
        }

        // ---- epilogue for this panel
        int pbase = (p0 + pp) * 64;
#pragma unroll
        for (int j = 0; j < 4; ++j) {
            int np = pbase + j * 16 + fr;
            if (np < Nreal) {
                if (OUTMODE == 3) {
                    int b = np / C_, c = np - b * C_;
                    float* ob = (float*)Out + (size_t)b * (P_ * C_) + c;
#pragma unroll
                    for (int i = 0; i < 2; ++i) {
#pragma unroll
                        for (int r = 0; r < 4; ++r) {
                            int m = smrow + i * 16 + kq * 4 + r;
                            if (m < Mreal)
                                ob[(size_t)m * C_] = acc[i][j][r] + bias[m];
                        }
                    }
                } else {
#pragma unroll
                    for (int i = 0; i < 2; ++i) {
                        int m = smrow + i * 16 + kq * 4;
                        size_t off = (size_t)np * MS + m;
                        if (OUTMODE == 1) {
                            *reinterpret_cast<f32x4*>((float*)Out + off) = acc[i][j];
                        } else {
                            float v[4];
#pragma unroll
                            for (int r = 0; r < 4; ++r) {
                                v[r] = acc[i][j][r];
                                if (ACT == 1) v[r] = fmaxf(v[r], 0.f);
                            }
                            if (OUTMODE == 2) {
                                f32x4 pr = *reinterpret_cast<const f32x4*>(partial + off);
#pragma unroll
                                for (int r = 0; r < 4; ++r)
                                    v[r] = 1.f / (1.f + __expf(-(v[r] + pr[r])));
                            }
                            ushort4 u;
                            u.x = f2b(v[0]); u.y = f2b(v[1]);
                            u.z = f2b(v[2]); u.w = f2b(v[3]);
                            *reinterpret_cast<ushort4*>((unsigned short*)Out + off) = u;
                        }
                    }
                }
            }
        }
        __syncthreads();   // drains vmcnt(0): next panel staged; all reads of buf done
        buf ^= 1;
    }
#undef STAGEP
}

extern "C" void kernel_launch(void* const* d_in, const int* in_sizes, int n_in,
                              void* d_out, int out_size, void* d_ws, size_t ws_size,
                              hipStream_t stream) {
    const float* x     = (const float*)d_in[0];
    const float* W1    = (const float*)d_in[1];
    const float* W2    = (const float*)d_in[2];
    const float* gamma = (const float*)d_in[3];
    const float* beta  = (const float*)d_in[4];
    const float* Wl    = (const float*)d_in[5];
    const float* bl    = (const float*)d_in[6];
    float* out = (float*)d_out;

    char* ws = (char*)d_ws;
    bf16*  Xc   = (bf16*)ws;                                  // MP_*512 bf16
    bf16*  Fn   = Xc + (size_t)MP_ * L_;                      // MP_*512 bf16 (Fn, later Prod)
    bf16*  Fq   = Fn + (size_t)MP_ * L_;                      // MP_*512 bf16 (freq, later fw)
    bf16*  Hb   = Fq + (size_t)MP_ * L_;                      // MP_*1024 bf16
    float* Ffp  = (float*)(Hb + (size_t)MP_ * H2_);           // MP_*512 f32 (C partial)
    bf16*  Dbf  = (bf16*)(Ffp + (size_t)MP_ * L_);            // 512*512
    bf16*  W1bf = Dbf + (size_t)L_ * L_;                      // 1024*512
    bf16*  W2bf = W1bf + (size_t)H2_ * L_;                    // 512*1024
    bf16*  Wlbf = W2bf + (size_t)L_ * H2_;                    // 768*512

    build_dct<<<(L_ * L_ + 255) / 256, 256, 0, stream>>>(Dbf);
    cvt_bf16<<<(H2_ * L_ + 255) / 256, 256, 0, stream>>>(W1, W1bf, H2_ * L_);
    cvt_bf16<<<(L_ * H2_ + 255) / 256, 256, 0, stream>>>(W2, W2bf, L_ * H2_);
    cvt_wl_pad<<<(PP_ * L_ + 255) / 256, 256, 0, stream>>>(Wl, Wlbf);
    transpose_x<<<dim3((C_ + 31) / 32, (L_ + 31) / 32, B_), 256, 0, stream>>>(x, Xc);

    // Stage A: freq[n,m] = Xc[n,:] . D[m,:]   (bf16 out)
    gemm_sw<0, 0><<<dim3(2, 216), 512, 0, stream>>>(
        Dbf, L_, Xc, L_, 0, nullptr, nullptr, Fq, L_, 2, M_, L_);
    layernorm_bf<false><<<M_, 256, 0, stream>>>(Fq, nullptr, gamma, beta, Fn);

    // Stage B: H[n,m] = relu(Fn[n,:] . W1[m,:])  (bf16 out, M'=1024)
    gemm_sw<1, 0><<<dim3(4, 216), 512, 0, stream>>>(
        W1bf, L_, Fn, L_, 0, nullptr, nullptr, Hb, H2_, 2, M_, H2_);

    // Stage C (K=1024 split): partial = H[:,0:512].W2[:,0:512]^T ; then add + sigmoid
    gemm_sw<0, 1><<<dim3(2, 216), 512, 0, stream>>>(
        W2bf, H2_, Hb, H2_, 0, nullptr, nullptr, Ffp, L_, 2, M_, L_);
    gemm_sw<0, 2><<<dim3(2, 216), 512, 0, stream>>>(
        W2bf, H2_, Hb, H2_, 512, Ffp, nullptr, Fq, L_, 2, M_, L_);
    // Prod = LN(fw) * Xc  (bf16, into Fn buffer)
    layernorm_bf<true><<<M_, 256, 0, stream>>>(Fq, Xc, gamma, beta, Fn);

    // Stage D: out[b,p,c] = Prod[(b,c),:] . Wl[p,:] + bl[p]  (scatter f32)
    gemm_sw<0, 3><<<dim3(3, 216), 512, 0, stream>>>(
        Wlbf, L_, Fn, L_, 0, nullptr, bl, out, PP_, 2, M_, P_);
}